// Round 1
// baseline (2130.835 us; speedup 1.0000x reference)
//
#include <hip/hip_runtime.h>
#include <math.h>

// AtomQueryFieldNet: NQ=4096 queries, NA=512 atoms, pair MLP 18->64->64->32->1,
// masked radial weighting -> per-query 3-vector -> 3->64->3 head.
// Strategy: thread = pair, activations in registers (fully unrolled), weights via
// wave-uniform global loads (compiler scalarizes to s_load; FMA = v_fmac v,s,v).

#define QPB 2  // queries per block (block = 256 threads = 4 waves)

__global__ __launch_bounds__(256, 2) void aqfn_kernel(
    const float* __restrict__ atom_pos,   // (512,3)
    const float* __restrict__ atom_feat,  // (512,2)
    const float* __restrict__ query_pos,  // (4096,3)
    const float* __restrict__ W1, const float* __restrict__ b1,  // (18,64),(64)
    const float* __restrict__ W2, const float* __restrict__ b2,  // (64,64),(64)
    const float* __restrict__ W3, const float* __restrict__ b3,  // (64,32),(32)
    const float* __restrict__ W4, const float* __restrict__ b4,  // (32,1),(1)
    const float* __restrict__ W5, const float* __restrict__ b5,  // (3,64),(64)
    const float* __restrict__ W6, const float* __restrict__ b6,  // (64,3),(3)
    float* __restrict__ out)              // (4096,3)
{
    const int tid  = threadIdx.x;
    const int wave = tid >> 6;
    const int lane = tid & 63;
    __shared__ float red[QPB][4][3];

    #pragma unroll 1
    for (int ql = 0; ql < QPB; ++ql) {
        const int q = blockIdx.x * QPB + ql;   // wave-uniform
        const float qx = query_pos[q*3+0];
        const float qy = query_pos[q*3+1];
        const float qz = query_pos[q*3+2];
        float wacc0 = 0.f, wacc1 = 0.f, wacc2 = 0.f;

        #pragma unroll 1
        for (int rep = 0; rep < 512/256; ++rep) {
            const int a = rep*256 + tid;
            const float rx = qx - atom_pos[a*3+0];
            const float ry = qy - atom_pos[a*3+1];
            const float rz = qz - atom_pos[a*3+2];
            // dist = norm(rel + 1e-12): match ref op order, no fma contraction
            const float ex = __fadd_rn(rx, 1e-12f);
            const float ey = __fadd_rn(ry, 1e-12f);
            const float ez = __fadd_rn(rz, 1e-12f);
            const float dd = __fadd_rn(__fadd_rn(__fmul_rn(ex,ex), __fmul_rn(ey,ey)),
                                       __fmul_rn(ez,ez));
            const float dist = sqrtf(dd);
            const float f0 = atom_feat[a*2+0];
            const float f1 = atom_feat[a*2+1];

            // ---- layer 1: x(18) @ W1(18,64) + b1, relu. x = [feat(2), rbf(16)] ----
            float h1[64];
            #pragma unroll
            for (int j = 0; j < 64; ++j)
                h1[j] = fmaf(f0, W1[j], fmaf(f1, W1[64+j], b1[j]));
            #pragma unroll
            for (int c = 0; c < 16; ++c) {
                const float t  = dist - 0.4f * (float)c;   // centers: linspace(0,6,16)
                const float xc = __expf(-10.0f * t * t);
                #pragma unroll
                for (int j = 0; j < 64; ++j)
                    h1[j] = fmaf(xc, W1[(2+c)*64 + j], h1[j]);
            }
            #pragma unroll
            for (int j = 0; j < 64; ++j) h1[j] = fmaxf(h1[j], 0.f);

            // ---- layer 2: h1(64) @ W2(64,64) + b2, relu ----
            float h2[64];
            #pragma unroll
            for (int j = 0; j < 64; ++j) h2[j] = b2[j];
            #pragma unroll
            for (int k = 0; k < 64; ++k) {
                const float hk = h1[k];
                #pragma unroll
                for (int j = 0; j < 64; ++j)
                    h2[j] = fmaf(hk, W2[k*64 + j], h2[j]);
            }
            #pragma unroll
            for (int j = 0; j < 64; ++j) h2[j] = fmaxf(h2[j], 0.f);

            // ---- layer 3: h2(64) @ W3(64,32) + b3, relu; layer 4: (32)@W4(32,1)+b4 ----
            float h3[32];
            #pragma unroll
            for (int m = 0; m < 32; ++m) h3[m] = b3[m];
            #pragma unroll
            for (int k = 0; k < 64; ++k) {
                const float hk = h2[k];
                #pragma unroll
                for (int m = 0; m < 32; ++m)
                    h3[m] = fmaf(hk, W3[k*32 + m], h3[m]);
            }
            float s = b4[0];
            #pragma unroll
            for (int m = 0; m < 32; ++m)
                s = fmaf(fmaxf(h3[m], 0.f), W4[m], s);

            // mask * scalar_w * dir_vec; dir uses rel (NOT rel+eps)
            const float inv = 1.0f / (dist + 1e-12f);
            const float wm  = (dist <= 6.0f) ? (s * inv) : 0.f;
            wacc0 = fmaf(wm, rx, wacc0);
            wacc1 = fmaf(wm, ry, wacc1);
            wacc2 = fmaf(wm, rz, wacc2);
        }

        // wave-level reduce (64 lanes)
        #pragma unroll
        for (int off = 32; off > 0; off >>= 1) {
            wacc0 += __shfl_down(wacc0, off);
            wacc1 += __shfl_down(wacc1, off);
            wacc2 += __shfl_down(wacc2, off);
        }
        if (lane == 0) {
            red[ql][wave][0] = wacc0;
            red[ql][wave][1] = wacc1;
            red[ql][wave][2] = wacc2;
        }
    }
    __syncthreads();

    // final head: wave w handles query (blockIdx*QPB + w); lane = hidden unit (64)
    if (wave < QPB) {
        const int q = blockIdx.x * QPB + wave;
        const float w0 = red[wave][0][0] + red[wave][1][0] + red[wave][2][0] + red[wave][3][0];
        const float w1v = red[wave][0][1] + red[wave][1][1] + red[wave][2][1] + red[wave][3][1];
        const float w2v = red[wave][0][2] + red[wave][1][2] + red[wave][2][2] + red[wave][3][2];
        float t = fmaf(w0,  W5[lane],
                  fmaf(w1v, W5[64+lane],
                  fmaf(w2v, W5[128+lane], b5[lane])));
        t = fmaxf(t, 0.f);
        float o0 = t * W6[lane*3+0];
        float o1 = t * W6[lane*3+1];
        float o2 = t * W6[lane*3+2];
        #pragma unroll
        for (int off = 32; off > 0; off >>= 1) {
            o0 += __shfl_down(o0, off);
            o1 += __shfl_down(o1, off);
            o2 += __shfl_down(o2, off);
        }
        if (lane == 0) {
            out[q*3+0] = o0 + b6[0];
            out[q*3+1] = o1 + b6[1];
            out[q*3+2] = o2 + b6[2];
        }
    }
}

extern "C" void kernel_launch(void* const* d_in, const int* in_sizes, int n_in,
                              void* d_out, int out_size, void* d_ws, size_t ws_size,
                              hipStream_t stream) {
    const float* atom_pos  = (const float*)d_in[0];
    const float* atom_feat = (const float*)d_in[1];
    const float* query_pos = (const float*)d_in[2];
    const float* W1 = (const float*)d_in[3];  const float* b1 = (const float*)d_in[4];
    const float* W2 = (const float*)d_in[5];  const float* b2 = (const float*)d_in[6];
    const float* W3 = (const float*)d_in[7];  const float* b3 = (const float*)d_in[8];
    const float* W4 = (const float*)d_in[9];  const float* b4 = (const float*)d_in[10];
    const float* W5 = (const float*)d_in[11]; const float* b5 = (const float*)d_in[12];
    const float* W6 = (const float*)d_in[13]; const float* b6 = (const float*)d_in[14];
    float* out = (float*)d_out;

    dim3 grid(4096 / QPB), block(256);
    hipLaunchKernelGGL(aqfn_kernel, grid, block, 0, stream,
                       atom_pos, atom_feat, query_pos,
                       W1,b1,W2,b2,W3,b3,W4,b4,W5,b5,W6,b6, out);
}

// Round 2
// 1501.350 us; speedup vs baseline: 1.4193x; 1.4193x over previous
//
#include <hip/hip_runtime.h>
#include <math.h>

// AtomQueryFieldNet: NQ=4096 queries, NA=512 atoms, pair MLP 18->64->64->32->1,
// masked radial weighting -> per-query 3-vector -> 3->64->3 head.
// Strategy: thread = pair, activations in registers (fully unrolled), weights via
// wave-uniform global loads (compiler scalarizes to s_load; FMA = v_fmac v,s,v).
//
// R1: __launch_bounds__(256,1). The (256,2) bound capped VGPRs at 128 and spilled
// h1[64]+h2[64] to scratch (rocprof: 484MB FETCH + 242MB WRITE of scratch traffic,
// 2130us). Peak liveness is ~128 activation floats + misc; allocator needs ~160-200.

#define QPB 2  // queries per block (block = 256 threads = 4 waves)

__global__ __launch_bounds__(256, 1) void aqfn_kernel(
    const float* __restrict__ atom_pos,   // (512,3)
    const float* __restrict__ atom_feat,  // (512,2)
    const float* __restrict__ query_pos,  // (4096,3)
    const float* __restrict__ W1, const float* __restrict__ b1,  // (18,64),(64)
    const float* __restrict__ W2, const float* __restrict__ b2,  // (64,64),(64)
    const float* __restrict__ W3, const float* __restrict__ b3,  // (64,32),(32)
    const float* __restrict__ W4, const float* __restrict__ b4,  // (32,1),(1)
    const float* __restrict__ W5, const float* __restrict__ b5,  // (3,64),(64)
    const float* __restrict__ W6, const float* __restrict__ b6,  // (64,3),(3)
    float* __restrict__ out)              // (4096,3)
{
    const int tid  = threadIdx.x;
    const int wave = tid >> 6;
    const int lane = tid & 63;
    __shared__ float red[QPB][4][3];

    #pragma unroll 1
    for (int ql = 0; ql < QPB; ++ql) {
        const int q = blockIdx.x * QPB + ql;   // wave-uniform
        const float qx = query_pos[q*3+0];
        const float qy = query_pos[q*3+1];
        const float qz = query_pos[q*3+2];
        float wacc0 = 0.f, wacc1 = 0.f, wacc2 = 0.f;

        #pragma unroll 1
        for (int rep = 0; rep < 512/256; ++rep) {
            const int a = rep*256 + tid;
            const float rx = qx - atom_pos[a*3+0];
            const float ry = qy - atom_pos[a*3+1];
            const float rz = qz - atom_pos[a*3+2];
            // dist = norm(rel + 1e-12): match ref op order, no fma contraction
            const float ex = __fadd_rn(rx, 1e-12f);
            const float ey = __fadd_rn(ry, 1e-12f);
            const float ez = __fadd_rn(rz, 1e-12f);
            const float dd = __fadd_rn(__fadd_rn(__fmul_rn(ex,ex), __fmul_rn(ey,ey)),
                                       __fmul_rn(ez,ez));
            const float dist = sqrtf(dd);
            const float f0 = atom_feat[a*2+0];
            const float f1 = atom_feat[a*2+1];

            // ---- layer 1: x(18) @ W1(18,64) + b1, relu. x = [feat(2), rbf(16)] ----
            float h1[64];
            #pragma unroll
            for (int j = 0; j < 64; ++j)
                h1[j] = fmaf(f0, W1[j], fmaf(f1, W1[64+j], b1[j]));
            #pragma unroll
            for (int c = 0; c < 16; ++c) {
                const float t  = dist - 0.4f * (float)c;   // centers: linspace(0,6,16)
                const float xc = __expf(-10.0f * t * t);
                #pragma unroll
                for (int j = 0; j < 64; ++j)
                    h1[j] = fmaf(xc, W1[(2+c)*64 + j], h1[j]);
            }
            #pragma unroll
            for (int j = 0; j < 64; ++j) h1[j] = fmaxf(h1[j], 0.f);

            // ---- layer 2: h1(64) @ W2(64,64) + b2, relu ----
            float h2[64];
            #pragma unroll
            for (int j = 0; j < 64; ++j) h2[j] = b2[j];
            #pragma unroll
            for (int k = 0; k < 64; ++k) {
                const float hk = h1[k];
                #pragma unroll
                for (int j = 0; j < 64; ++j)
                    h2[j] = fmaf(hk, W2[k*64 + j], h2[j]);
            }
            #pragma unroll
            for (int j = 0; j < 64; ++j) h2[j] = fmaxf(h2[j], 0.f);

            // ---- layer 3: h2(64) @ W3(64,32) + b3, relu; layer 4: (32)@W4(32,1)+b4 ----
            float h3[32];
            #pragma unroll
            for (int m = 0; m < 32; ++m) h3[m] = b3[m];
            #pragma unroll
            for (int k = 0; k < 64; ++k) {
                const float hk = h2[k];
                #pragma unroll
                for (int m = 0; m < 32; ++m)
                    h3[m] = fmaf(hk, W3[k*32 + m], h3[m]);
            }
            float s = b4[0];
            #pragma unroll
            for (int m = 0; m < 32; ++m)
                s = fmaf(fmaxf(h3[m], 0.f), W4[m], s);

            // mask * scalar_w * dir_vec; dir uses rel (NOT rel+eps)
            const float inv = 1.0f / (dist + 1e-12f);
            const float wm  = (dist <= 6.0f) ? (s * inv) : 0.f;
            wacc0 = fmaf(wm, rx, wacc0);
            wacc1 = fmaf(wm, ry, wacc1);
            wacc2 = fmaf(wm, rz, wacc2);
        }

        // wave-level reduce (64 lanes)
        #pragma unroll
        for (int off = 32; off > 0; off >>= 1) {
            wacc0 += __shfl_down(wacc0, off);
            wacc1 += __shfl_down(wacc1, off);
            wacc2 += __shfl_down(wacc2, off);
        }
        if (lane == 0) {
            red[ql][wave][0] = wacc0;
            red[ql][wave][1] = wacc1;
            red[ql][wave][2] = wacc2;
        }
    }
    __syncthreads();

    // final head: wave w handles query (blockIdx*QPB + w); lane = hidden unit (64)
    if (wave < QPB) {
        const int q = blockIdx.x * QPB + wave;
        const float w0 = red[wave][0][0] + red[wave][1][0] + red[wave][2][0] + red[wave][3][0];
        const float w1v = red[wave][0][1] + red[wave][1][1] + red[wave][2][1] + red[wave][3][1];
        const float w2v = red[wave][0][2] + red[wave][1][2] + red[wave][2][2] + red[wave][3][2];
        float t = fmaf(w0,  W5[lane],
                  fmaf(w1v, W5[64+lane],
                  fmaf(w2v, W5[128+lane], b5[lane])));
        t = fmaxf(t, 0.f);
        float o0 = t * W6[lane*3+0];
        float o1 = t * W6[lane*3+1];
        float o2 = t * W6[lane*3+2];
        #pragma unroll
        for (int off = 32; off > 0; off >>= 1) {
            o0 += __shfl_down(o0, off);
            o1 += __shfl_down(o1, off);
            o2 += __shfl_down(o2, off);
        }
        if (lane == 0) {
            out[q*3+0] = o0 + b6[0];
            out[q*3+1] = o1 + b6[1];
            out[q*3+2] = o2 + b6[2];
        }
    }
}

extern "C" void kernel_launch(void* const* d_in, const int* in_sizes, int n_in,
                              void* d_out, int out_size, void* d_ws, size_t ws_size,
                              hipStream_t stream) {
    const float* atom_pos  = (const float*)d_in[0];
    const float* atom_feat = (const float*)d_in[1];
    const float* query_pos = (const float*)d_in[2];
    const float* W1 = (const float*)d_in[3];  const float* b1 = (const float*)d_in[4];
    const float* W2 = (const float*)d_in[5];  const float* b2 = (const float*)d_in[6];
    const float* W3 = (const float*)d_in[7];  const float* b3 = (const float*)d_in[8];
    const float* W4 = (const float*)d_in[9];  const float* b4 = (const float*)d_in[10];
    const float* W5 = (const float*)d_in[11]; const float* b5 = (const float*)d_in[12];
    const float* W6 = (const float*)d_in[13]; const float* b6 = (const float*)d_in[14];
    float* out = (float*)d_out;

    dim3 grid(4096 / QPB), block(256);
    hipLaunchKernelGGL(aqfn_kernel, grid, block, 0, stream,
                       atom_pos, atom_feat, query_pos,
                       W1,b1,W2,b2,W3,b3,W4,b4,W5,b5,W6,b6, out);
}